// Round 1
// baseline (537.638 us; speedup 1.0000x reference)
//
#include <hip/hip_runtime.h>

typedef __attribute__((ext_vector_type(8))) short short8;
typedef __attribute__((ext_vector_type(4))) float f32x4;

#define B_   2
#define C_   192
#define NH_  4
#define HD_  48
#define CO_  576
#define HGT_ 256
#define WID_ 256
#define NSP_ 65536

__device__ __forceinline__ unsigned short f2bf(float f) {
  unsigned int u = __float_as_uint(f);
  u += 0x7FFFu + ((u >> 16) & 1u);   // RNE; inputs are normal floats
  return (unsigned short)(u >> 16);
}
__device__ __forceinline__ float bf2f(unsigned short h) {
  return __uint_as_float(((unsigned int)h) << 16);
}
__device__ __forceinline__ int swz(int n) { return (n & 7) ^ ((n >> 3) & 7); }

// ---------------------------------------------------------------- K0: fp32 -> bf16
__global__ void k_cvt(const float* __restrict__ src, unsigned short* __restrict__ dst, int n) {
  int i = blockIdx.x * 256 + threadIdx.x;
  if (i < n) dst[i] = f2bf(src[i]);
}

// ---------------------------------------------------------------- GEMM: out[b][m][n] = sum_k A[m][k] * X[b][k+chanOff][n]
// A: bf16 row-major [M][192]. X: [b][.][NSP] fp32 or bf16. BM=192 (mb blocks), BN=64, K=192.
// 256 threads = 4 waves (2m x 2n), wave tile 96x32 => 6x2 frags of 16x16x32 MFMA.
template<int MBLOCKS, bool X_BF16, bool OUT_BF16>
__global__ __launch_bounds__(256)
void k_gemm(const unsigned short* __restrict__ A, long aBatchStride,
            const void* __restrict__ Xin, long xBatchStride, int xChanOff,
            void* __restrict__ Out, long outBatchStride)
{
  __shared__ unsigned short Xs[64 * 192];   // Xs[n][k], XOR-swizzled in 16B units
  const int tid = threadIdx.x;
  const int b = blockIdx.z;
  int mb, nb;
  if (MBLOCKS == 3) {                        // keep the 3 m-blocks sharing an X panel on one XCD
    int lin = blockIdx.x;
    int xcd = lin & 7, rest = lin >> 3;
    mb = rest % 3; nb = (rest / 3) * 8 + xcd;
  } else { mb = 0; nb = blockIdx.x; }

  // ---- stage X panel (192 k-rows x 64 n-cols) -> Xs[n][k] bf16 via 4x4 in-register transpose
  if (!X_BF16) {
    const float* X = (const float*)Xin + (size_t)b * xBatchStride + (size_t)xChanOff * NSP_ + (size_t)nb * 64;
#pragma unroll
    for (int it = 0; it < 3; it++) {
      int s = tid + it * 256;                // 768 subtiles of 4k x 4n
      int sn = s & 15, sk = s >> 4;
      int n0 = sn * 4, k0 = sk * 4;
      const float* p = X + (size_t)k0 * NSP_ + n0;
      float4 r0 = *(const float4*)(p);
      float4 r1 = *(const float4*)(p + NSP_);
      float4 r2 = *(const float4*)(p + 2 * NSP_);
      float4 r3 = *(const float4*)(p + 3 * NSP_);
      int u16 = k0 >> 3, hh = (k0 >> 2) & 1;
#define WRCOL(J, F) { int n = n0 + (J);                                         \
      unsigned short* q = &Xs[n * 192 + ((u16 ^ swz(n)) << 3) + (hh << 2)];     \
      ushort4 w; w.x = f2bf(r0.F); w.y = f2bf(r1.F); w.z = f2bf(r2.F); w.w = f2bf(r3.F); \
      *(ushort4*)q = w; }
      WRCOL(0, x) WRCOL(1, y) WRCOL(2, z) WRCOL(3, w)
#undef WRCOL
    }
  } else {
    const unsigned short* X = (const unsigned short*)Xin + (size_t)b * xBatchStride + (size_t)xChanOff * NSP_ + (size_t)nb * 64;
#pragma unroll
    for (int it = 0; it < 3; it++) {
      int s = tid + it * 256;
      int sn = s & 15, sk = s >> 4;
      int n0 = sn * 4, k0 = sk * 4;
      const unsigned short* p = X + (size_t)k0 * NSP_ + n0;
      ushort4 r0 = *(const ushort4*)(p);
      ushort4 r1 = *(const ushort4*)(p + NSP_);
      ushort4 r2 = *(const ushort4*)(p + 2 * NSP_);
      ushort4 r3 = *(const ushort4*)(p + 3 * NSP_);
      int u16 = k0 >> 3, hh = (k0 >> 2) & 1;
#define WRCOLU(J, F) { int n = n0 + (J);                                        \
      unsigned short* q = &Xs[n * 192 + ((u16 ^ swz(n)) << 3) + (hh << 2)];     \
      ushort4 w; w.x = r0.F; w.y = r1.F; w.z = r2.F; w.w = r3.F;                \
      *(ushort4*)q = w; }
      WRCOLU(0, x) WRCOLU(1, y) WRCOLU(2, z) WRCOLU(3, w)
#undef WRCOLU
    }
  }
  __syncthreads();

  const int wave = tid >> 6, lane = tid & 63;
  const int wm = wave >> 1, wn = wave & 1;
  const int l15 = lane & 15, lg = lane >> 4;
  const int rowbase = mb * 192 + wm * 96;
  const int colbase = wn * 32;
  const unsigned short* Ab = A + (size_t)b * aBatchStride;

  f32x4 acc[6][2];
#pragma unroll
  for (int i = 0; i < 6; i++)
#pragma unroll
    for (int j = 0; j < 2; j++) acc[i][j] = (f32x4){0.f, 0.f, 0.f, 0.f};

#pragma unroll
  for (int kk = 0; kk < 6; kk++) {
    const int k0 = kk * 32 + lg * 8;
    short8 af[6];
#pragma unroll
    for (int fm = 0; fm < 6; fm++) {
      int row = rowbase + fm * 16 + l15;
      af[fm] = *(const short8*)(Ab + (size_t)row * 192 + k0);
    }
    short8 bfr[2];
#pragma unroll
    for (int fn = 0; fn < 2; fn++) {
      int col = colbase + fn * 16 + l15;
      bfr[fn] = *(const short8*)(&Xs[col * 192 + (((k0 >> 3) ^ swz(col)) << 3)]);
    }
#pragma unroll
    for (int fm = 0; fm < 6; fm++)
#pragma unroll
      for (int fn = 0; fn < 2; fn++)
        acc[fm][fn] = __builtin_amdgcn_mfma_f32_16x16x32_bf16(af[fm], bfr[fn], acc[fm][fn], 0, 0, 0);
  }

  const size_t ncol0 = (size_t)nb * 64 + colbase;
  if (OUT_BF16) {
    unsigned short* O = (unsigned short*)Out + (size_t)b * outBatchStride;
#pragma unroll
    for (int fm = 0; fm < 6; fm++)
#pragma unroll
      for (int r = 0; r < 4; r++) {
        int row = rowbase + fm * 16 + lg * 4 + r;
#pragma unroll
        for (int fn = 0; fn < 2; fn++)
          O[(size_t)row * NSP_ + ncol0 + fn * 16 + l15] = f2bf(acc[fm][fn][r]);
      }
  } else {
    float* O = (float*)Out + (size_t)b * outBatchStride;
#pragma unroll
    for (int fm = 0; fm < 6; fm++)
#pragma unroll
      for (int r = 0; r < 4; r++) {
        int row = rowbase + fm * 16 + lg * 4 + r;
#pragma unroll
        for (int fn = 0; fn < 2; fn++)
          O[(size_t)row * NSP_ + ncol0 + fn * 16 + l15] = acc[fm][fn][r];
      }
  }
}

// ---------------------------------------------------------------- K2: depthwise 3x3 (pad 1) + sumsq of q,k channels
__global__ __launch_bounds__(256)
void k_dw(const unsigned short* __restrict__ qkv, const float* __restrict__ dww,
          unsigned short* __restrict__ out, float* __restrict__ sumsq)
{
  const int y0 = blockIdx.x * 4;
  const int ch = blockIdx.y;
  const int b  = blockIdx.z;
  const int x  = threadIdx.x;                 // 0..255 = full row
  const unsigned short* in = qkv + ((size_t)b * CO_ + ch) * NSP_;
  float w[9];
#pragma unroll
  for (int i = 0; i < 9; i++) w[i] = dww[ch * 9 + i];

  __shared__ float rows[6][WID_ + 2];
#pragma unroll
  for (int r = 0; r < 6; r++) {
    int yy = y0 - 1 + r;
    float v = 0.f;
    if (yy >= 0 && yy < HGT_) v = bf2f(in[yy * WID_ + x]);
    rows[r][x + 1] = v;
  }
  if (x < 12) {                               // zero halo cols
    int r = x >> 1, c = (x & 1) ? (WID_ + 1) : 0;
    rows[r][c] = 0.f;
  }
  __syncthreads();

  unsigned short* o = out + ((size_t)b * CO_ + ch) * NSP_;
  float ss = 0.f;
#pragma unroll
  for (int r = 0; r < 4; r++) {
    float a =
      rows[r + 0][x + 0] * w[0] + rows[r + 0][x + 1] * w[1] + rows[r + 0][x + 2] * w[2] +
      rows[r + 1][x + 0] * w[3] + rows[r + 1][x + 1] * w[4] + rows[r + 1][x + 2] * w[5] +
      rows[r + 2][x + 0] * w[6] + rows[r + 2][x + 1] * w[7] + rows[r + 2][x + 2] * w[8];
    o[(size_t)(y0 + r) * WID_ + x] = f2bf(a);
    ss += a * a;
  }
  if (ch < 2 * C_) {                          // only q,k channels need norms
#pragma unroll
    for (int off = 32; off > 0; off >>= 1) ss += __shfl_down(ss, off);
    __shared__ float wsum[4];
    if ((x & 63) == 0) wsum[x >> 6] = ss;
    __syncthreads();
    if (x == 0) atomicAdd(&sumsq[b * 2 * C_ + ch], wsum[0] + wsum[1] + wsum[2] + wsum[3]);
  }
}

// ---------------------------------------------------------------- K3: per-(b,h) q.k^T partials over n-chunks (MFMA)
__global__ __launch_bounds__(256)
void k_qk(const unsigned short* __restrict__ qkvd, float* __restrict__ part)
{
  const int chunk = blockIdx.x;               // 64 chunks of 1024 n
  const int h = blockIdx.y, b = blockIdx.z;
  const int wave = threadIdx.x >> 6, lane = threadIdx.x & 63;
  const int l15 = lane & 15, lg = lane >> 4;
  const unsigned short* qb = qkvd + (size_t)b * CO_ * NSP_ + (size_t)(h * HD_) * NSP_;
  const unsigned short* kb = qkvd + (size_t)b * CO_ * NSP_ + (size_t)(C_ + h * HD_) * NSP_;
  const int kbase = chunk * 1024 + wave * 256;

  f32x4 acc[3][3];
#pragma unroll
  for (int i = 0; i < 3; i++)
#pragma unroll
    for (int j = 0; j < 3; j++) acc[i][j] = (f32x4){0.f, 0.f, 0.f, 0.f};

#pragma unroll
  for (int ks = 0; ks < 8; ks++) {
    const int k0 = kbase + ks * 32 + lg * 8;
    short8 af[3], bfr[3];
#pragma unroll
    for (int i = 0; i < 3; i++)
      af[i] = *(const short8*)(qb + (size_t)(i * 16 + l15) * NSP_ + k0);
#pragma unroll
    for (int i = 0; i < 3; i++)
      bfr[i] = *(const short8*)(kb + (size_t)(i * 16 + l15) * NSP_ + k0);
#pragma unroll
    for (int fm = 0; fm < 3; fm++)
#pragma unroll
      for (int fn = 0; fn < 3; fn++)
        acc[fm][fn] = __builtin_amdgcn_mfma_f32_16x16x32_bf16(af[fm], bfr[fn], acc[fm][fn], 0, 0, 0);
  }
  float* P = part + ((((size_t)b * NH_ + h) * 64 + chunk) * 4 + wave) * (HD_ * HD_);
#pragma unroll
  for (int fm = 0; fm < 3; fm++)
#pragma unroll
    for (int fn = 0; fn < 3; fn++)
#pragma unroll
      for (int r = 0; r < 4; r++)
        P[(fm * 16 + lg * 4 + r) * HD_ + fn * 16 + l15] = acc[fm][fn][r];
}

// ---------------------------------------------------------------- K4: reduce partials, scale by 1/(|q||k|)*temp, softmax,
//      compose M[b] = proj_w @ blockdiag(attn)  (bf16 out)
__global__ __launch_bounds__(256)
void k_smax(const float* __restrict__ part, const float* __restrict__ sumsq,
            const float* __restrict__ temp, const float* __restrict__ projw,
            unsigned short* __restrict__ M)
{
  const int h = blockIdx.x, b = blockIdx.y;
  const int tid = threadIdx.x;
  __shared__ float lgt[HD_][HD_];
  __shared__ float at[HD_][HD_];
  __shared__ float pw[C_][HD_];
  const float tmp = temp[h];
  const float* P = part + ((size_t)(b * NH_ + h)) * 256 * (HD_ * HD_);

  for (int e = tid; e < HD_ * HD_; e += 256) {
    float s = 0.f;
    for (int p = 0; p < 256; p++) s += P[(size_t)p * (HD_ * HD_) + e];
    int c = e / HD_, d = e % HD_;
    float nq = fmaxf(sqrtf(sumsq[b * 2 * C_ + h * HD_ + c]), 1e-12f);
    float nk = fmaxf(sqrtf(sumsq[b * 2 * C_ + C_ + h * HD_ + d]), 1e-12f);
    lgt[c][d] = s / (nq * nk) * tmp;
  }
  for (int e = tid; e < C_ * HD_; e += 256) {
    int o = e / HD_, c = e % HD_;
    pw[o][c] = projw[o * C_ + h * HD_ + c];
  }
  __syncthreads();
  if (tid < HD_) {
    float mx = -1e30f;
    for (int d = 0; d < HD_; d++) mx = fmaxf(mx, lgt[tid][d]);
    float s = 0.f;
    for (int d = 0; d < HD_; d++) { float e_ = expf(lgt[tid][d] - mx); at[tid][d] = e_; s += e_; }
    float inv = 1.f / s;
    for (int d = 0; d < HD_; d++) at[tid][d] *= inv;
  }
  __syncthreads();
  unsigned short* Mo = M + (size_t)b * C_ * C_;
  for (int e = tid; e < C_ * HD_; e += 256) {
    int o = e / HD_, d = e % HD_;
    float s = 0.f;
    for (int c = 0; c < HD_; c++) s += pw[o][c] * at[c][d];
    Mo[o * C_ + h * HD_ + d] = f2bf(s);
  }
}

// ----------------------------------------------------------------
extern "C" void kernel_launch(void* const* d_in, const int* in_sizes, int n_in,
                              void* d_out, int out_size, void* d_ws, size_t ws_size,
                              hipStream_t stream)
{
  const float* x     = (const float*)d_in[0];
  const float* qkvw  = (const float*)d_in[1];
  const float* dww   = (const float*)d_in[2];
  const float* projw = (const float*)d_in[3];
  const float* temp  = (const float*)d_in[4];
  float* out         = (float*)d_out;

  char* ws = (char*)d_ws;
  size_t off = 0;
  auto alloc = [&](size_t bytes) { void* p = ws + off; off += (bytes + 255) & ~(size_t)255; return p; };
  unsigned short* qkvw_bf = (unsigned short*)alloc((size_t)CO_ * C_ * 2);
  unsigned short* M_bf    = (unsigned short*)alloc((size_t)B_ * C_ * C_ * 2);
  float* sumsq            = (float*)alloc((size_t)B_ * 2 * C_ * 4);
  float* part             = (float*)alloc((size_t)B_ * NH_ * 256 * HD_ * HD_ * 4);
  unsigned short* qkv_bf  = (unsigned short*)alloc((size_t)B_ * CO_ * NSP_ * 2);
  unsigned short* qkvd_bf = (unsigned short*)alloc((size_t)B_ * CO_ * NSP_ * 2);

  hipMemsetAsync(sumsq, 0, (size_t)B_ * 2 * C_ * 4, stream);
  k_cvt<<<dim3((CO_ * C_ + 255) / 256), dim3(256), 0, stream>>>(qkvw, qkvw_bf, CO_ * C_);
  // K1: qkv = qkv_w @ x    (M=576 via 3 m-blocks, bf16 out)
  k_gemm<3, false, true><<<dim3(3 * 1024, 1, B_), dim3(256), 0, stream>>>(
      qkvw_bf, 0, x, (long)C_ * NSP_, 0, qkv_bf, (long)CO_ * NSP_);
  // K2: depthwise 3x3 + q/k sum-of-squares
  k_dw<<<dim3(HGT_ / 4, CO_, B_), dim3(256), 0, stream>>>(qkv_bf, dww, qkvd_bf, sumsq);
  // K3: q.k^T partials
  k_qk<<<dim3(64, NH_, B_), dim3(256), 0, stream>>>(qkvd_bf, part);
  // K4: softmax + fold proj_w -> M[b] (192x192 bf16)
  k_smax<<<dim3(NH_, B_), dim3(256), 0, stream>>>(part, sumsq, temp, projw, M_bf);
  // K5: out = M[b] @ v   (fp32 out to d_out)
  k_gemm<1, true, false><<<dim3(1024, 1, B_), dim3(256), 0, stream>>>(
      M_bf, (long)C_ * C_, qkvd_bf, (long)CO_ * NSP_, 2 * C_, out, (long)C_ * NSP_);
}

// Round 2
// 453.166 us; speedup vs baseline: 1.1864x; 1.1864x over previous
//
#include <hip/hip_runtime.h>

typedef __attribute__((ext_vector_type(8))) short short8;
typedef __attribute__((ext_vector_type(4))) float f32x4;

#define B_   2
#define C_   192
#define NH_  4
#define HD_  48
#define CO_  576
#define HGT_ 256
#define WID_ 256
#define NSP_ 65536

__device__ __forceinline__ unsigned short f2bf(float f) {
  unsigned int u = __float_as_uint(f);
  u += 0x7FFFu + ((u >> 16) & 1u);   // RNE; inputs are normal floats
  return (unsigned short)(u >> 16);
}
__device__ __forceinline__ float bf2f(unsigned short h) {
  return __uint_as_float(((unsigned int)h) << 16);
}
__device__ __forceinline__ int swz(int n) { return (n & 7) ^ ((n >> 3) & 7); }

// ---------------------------------------------------------------- K0: fp32 -> bf16
__global__ void k_cvt(const float* __restrict__ src, unsigned short* __restrict__ dst, int n) {
  int i = blockIdx.x * 256 + threadIdx.x;
  if (i < n) dst[i] = f2bf(src[i]);
}

// ---------------------------------------------------------------- GEMM: out[b][m][n] = sum_k A[m][k] * X[b][k+chanOff][n]
// A: bf16 row-major [M][192]. X: [b][.][NSP] fp32 or bf16. BM=192 (mb blocks), BN=64, K=192.
// 256 threads = 4 waves (2m x 2n), wave tile 96x32 => 6x2 frags of 16x16x32 MFMA.
template<int MBLOCKS, bool X_BF16, bool OUT_BF16>
__global__ __launch_bounds__(256)
void k_gemm(const unsigned short* __restrict__ A, long aBatchStride,
            const void* __restrict__ Xin, long xBatchStride, int xChanOff,
            void* __restrict__ Out, long outBatchStride)
{
  __shared__ unsigned short Xs[64 * 192];   // Xs[n][k], XOR-swizzled in 16B units
  const int tid = threadIdx.x;
  const int b = blockIdx.z;
  int mb, nb;
  if (MBLOCKS == 3) {                        // keep the 3 m-blocks sharing an X panel on one XCD
    int lin = blockIdx.x;
    int xcd = lin & 7, rest = lin >> 3;
    mb = rest % 3; nb = (rest / 3) * 8 + xcd;
  } else { mb = 0; nb = blockIdx.x; }

  // ---- stage X panel (192 k-rows x 64 n-cols) -> Xs[n][k] bf16 via 4x4 in-register transpose
  if (!X_BF16) {
    const float* X = (const float*)Xin + (size_t)b * xBatchStride + (size_t)xChanOff * NSP_ + (size_t)nb * 64;
#pragma unroll
    for (int it = 0; it < 3; it++) {
      int s = tid + it * 256;                // 768 subtiles of 4k x 4n
      int sn = s & 15, sk = s >> 4;
      int n0 = sn * 4, k0 = sk * 4;
      const float* p = X + (size_t)k0 * NSP_ + n0;
      float4 r0 = *(const float4*)(p);
      float4 r1 = *(const float4*)(p + NSP_);
      float4 r2 = *(const float4*)(p + 2 * NSP_);
      float4 r3 = *(const float4*)(p + 3 * NSP_);
      int u16 = k0 >> 3, hh = (k0 >> 2) & 1;
#define WRCOL(J, F) { int n = n0 + (J);                                         \
      unsigned short* q = &Xs[n * 192 + ((u16 ^ swz(n)) << 3) + (hh << 2)];     \
      ushort4 w; w.x = f2bf(r0.F); w.y = f2bf(r1.F); w.z = f2bf(r2.F); w.w = f2bf(r3.F); \
      *(ushort4*)q = w; }
      WRCOL(0, x) WRCOL(1, y) WRCOL(2, z) WRCOL(3, w)
#undef WRCOL
    }
  } else {
    const unsigned short* X = (const unsigned short*)Xin + (size_t)b * xBatchStride + (size_t)xChanOff * NSP_ + (size_t)nb * 64;
#pragma unroll
    for (int it = 0; it < 3; it++) {
      int s = tid + it * 256;
      int sn = s & 15, sk = s >> 4;
      int n0 = sn * 4, k0 = sk * 4;
      const unsigned short* p = X + (size_t)k0 * NSP_ + n0;
      ushort4 r0 = *(const ushort4*)(p);
      ushort4 r1 = *(const ushort4*)(p + NSP_);
      ushort4 r2 = *(const ushort4*)(p + 2 * NSP_);
      ushort4 r3 = *(const ushort4*)(p + 3 * NSP_);
      int u16 = k0 >> 3, hh = (k0 >> 2) & 1;
#define WRCOLU(J, F) { int n = n0 + (J);                                        \
      unsigned short* q = &Xs[n * 192 + ((u16 ^ swz(n)) << 3) + (hh << 2)];     \
      ushort4 w; w.x = r0.F; w.y = r1.F; w.z = r2.F; w.w = r3.F;                \
      *(ushort4*)q = w; }
      WRCOLU(0, x) WRCOLU(1, y) WRCOLU(2, z) WRCOLU(3, w)
#undef WRCOLU
    }
  }
  __syncthreads();

  const int wave = tid >> 6, lane = tid & 63;
  const int wm = wave >> 1, wn = wave & 1;
  const int l15 = lane & 15, lg = lane >> 4;
  const int rowbase = mb * 192 + wm * 96;
  const int colbase = wn * 32;
  const unsigned short* Ab = A + (size_t)b * aBatchStride;

  f32x4 acc[6][2];
#pragma unroll
  for (int i = 0; i < 6; i++)
#pragma unroll
    for (int j = 0; j < 2; j++) acc[i][j] = (f32x4){0.f, 0.f, 0.f, 0.f};

#pragma unroll
  for (int kk = 0; kk < 6; kk++) {
    const int k0 = kk * 32 + lg * 8;
    short8 af[6];
#pragma unroll
    for (int fm = 0; fm < 6; fm++) {
      int row = rowbase + fm * 16 + l15;
      af[fm] = *(const short8*)(Ab + (size_t)row * 192 + k0);
    }
    short8 bfr[2];
#pragma unroll
    for (int fn = 0; fn < 2; fn++) {
      int col = colbase + fn * 16 + l15;
      bfr[fn] = *(const short8*)(&Xs[col * 192 + (((k0 >> 3) ^ swz(col)) << 3)]);
    }
#pragma unroll
    for (int fm = 0; fm < 6; fm++)
#pragma unroll
      for (int fn = 0; fn < 2; fn++)
        acc[fm][fn] = __builtin_amdgcn_mfma_f32_16x16x32_bf16(af[fm], bfr[fn], acc[fm][fn], 0, 0, 0);
  }

  const size_t ncol0 = (size_t)nb * 64 + colbase;
  if (OUT_BF16) {
    unsigned short* O = (unsigned short*)Out + (size_t)b * outBatchStride;
#pragma unroll
    for (int fm = 0; fm < 6; fm++)
#pragma unroll
      for (int r = 0; r < 4; r++) {
        int row = rowbase + fm * 16 + lg * 4 + r;
#pragma unroll
        for (int fn = 0; fn < 2; fn++)
          O[(size_t)row * NSP_ + ncol0 + fn * 16 + l15] = f2bf(acc[fm][fn][r]);
      }
  } else {
    float* O = (float*)Out + (size_t)b * outBatchStride;
#pragma unroll
    for (int fm = 0; fm < 6; fm++)
#pragma unroll
      for (int r = 0; r < 4; r++) {
        int row = rowbase + fm * 16 + lg * 4 + r;
#pragma unroll
        for (int fn = 0; fn < 2; fn++)
          O[(size_t)row * NSP_ + ncol0 + fn * 16 + l15] = acc[fm][fn][r];
      }
  }
}

// ---------------------------------------------------------------- K2: depthwise 3x3 (pad 1) + sumsq of q,k channels
// No LDS staging: short8 vector loads, horizontal halo via __shfl within
// 32-lane groups, vertical halo via rolling 3-row register window.
// Block: 256 threads = 32 col-segments x 8 row-blocks; 16 output rows/thread.
#define DW_RT 16
__global__ __launch_bounds__(256)
void k_dw(const unsigned short* __restrict__ qkv, const float* __restrict__ dww,
          unsigned short* __restrict__ out, float* __restrict__ sumsq)
{
  const int ch = blockIdx.y;
  const int b  = blockIdx.z;
  const int tid = threadIdx.x;
  const int seg = tid & 31;                  // column segment (8 px)
  const int rb  = tid >> 5;                  // row-block 0..7
  const int ybase = blockIdx.x * (8 * DW_RT) + rb * DW_RT;

  const unsigned short* in = qkv + ((size_t)b * CO_ + ch) * NSP_;
  unsigned short* o = out + ((size_t)b * CO_ + ch) * NSP_;
  float w[9];
#pragma unroll
  for (int i = 0; i < 9; i++) w[i] = dww[ch * 9 + i];

  float rw[3][10];
  float ss = 0.f;
#pragma unroll
  for (int i = 0; i < DW_RT + 2; i++) {
    const int yy = ybase - 1 + i;
    float* f = rw[i % 3];
    if ((unsigned)yy < (unsigned)HGT_) {
      short8 v = *(const short8*)(in + (size_t)yy * WID_ + seg * 8);
#pragma unroll
      for (int j = 0; j < 8; j++) f[j + 1] = bf2f((unsigned short)v[j]);
    } else {
#pragma unroll
      for (int j = 0; j < 8; j++) f[j + 1] = 0.f;
    }
    float lf = __shfl_up(f[8], 1, 32);
    float rt = __shfl_down(f[1], 1, 32);
    f[0] = (seg == 0)  ? 0.f : lf;
    f[9] = (seg == 31) ? 0.f : rt;
    if (i >= 2) {
      const float* a  = rw[(i - 2) % 3];
      const float* bb = rw[(i - 1) % 3];
      const float* cc = f;
      short8 ov;
#pragma unroll
      for (int j = 0; j < 8; j++) {
        float acc = a[j]  * w[0] + a[j + 1]  * w[1] + a[j + 2]  * w[2]
                  + bb[j] * w[3] + bb[j + 1] * w[4] + bb[j + 2] * w[5]
                  + cc[j] * w[6] + cc[j + 1] * w[7] + cc[j + 2] * w[8];
        ov[j] = (short)f2bf(acc);
        ss += acc * acc;
      }
      *(short8*)(o + (size_t)(yy - 1) * WID_ + seg * 8) = ov;
    }
  }

  if (ch < 2 * C_) {                          // only q,k channels need norms
#pragma unroll
    for (int off = 32; off > 0; off >>= 1) ss += __shfl_down(ss, off);
    __shared__ float wsum[4];
    if ((tid & 63) == 0) wsum[tid >> 6] = ss;
    __syncthreads();
    if (tid == 0) atomicAdd(&sumsq[b * 2 * C_ + ch], wsum[0] + wsum[1] + wsum[2] + wsum[3]);
  }
}

// ---------------------------------------------------------------- K3: per-(b,h) q.k^T partials over n-chunks (MFMA)
__global__ __launch_bounds__(256)
void k_qk(const unsigned short* __restrict__ qkvd, float* __restrict__ part)
{
  const int chunk = blockIdx.x;               // 64 chunks of 1024 n
  const int h = blockIdx.y, b = blockIdx.z;
  const int wave = threadIdx.x >> 6, lane = threadIdx.x & 63;
  const int l15 = lane & 15, lg = lane >> 4;
  const unsigned short* qb = qkvd + (size_t)b * CO_ * NSP_ + (size_t)(h * HD_) * NSP_;
  const unsigned short* kb = qkvd + (size_t)b * CO_ * NSP_ + (size_t)(C_ + h * HD_) * NSP_;
  const int kbase = chunk * 1024 + wave * 256;

  f32x4 acc[3][3];
#pragma unroll
  for (int i = 0; i < 3; i++)
#pragma unroll
    for (int j = 0; j < 3; j++) acc[i][j] = (f32x4){0.f, 0.f, 0.f, 0.f};

#pragma unroll
  for (int ks = 0; ks < 8; ks++) {
    const int k0 = kbase + ks * 32 + lg * 8;
    short8 af[3], bfr[3];
#pragma unroll
    for (int i = 0; i < 3; i++)
      af[i] = *(const short8*)(qb + (size_t)(i * 16 + l15) * NSP_ + k0);
#pragma unroll
    for (int i = 0; i < 3; i++)
      bfr[i] = *(const short8*)(kb + (size_t)(i * 16 + l15) * NSP_ + k0);
#pragma unroll
    for (int fm = 0; fm < 3; fm++)
#pragma unroll
      for (int fn = 0; fn < 3; fn++)
        acc[fm][fn] = __builtin_amdgcn_mfma_f32_16x16x32_bf16(af[fm], bfr[fn], acc[fm][fn], 0, 0, 0);
  }
  float* P = part + ((((size_t)b * NH_ + h) * 64 + chunk) * 4 + wave) * (HD_ * HD_);
#pragma unroll
  for (int fm = 0; fm < 3; fm++)
#pragma unroll
    for (int fn = 0; fn < 3; fn++)
#pragma unroll
      for (int r = 0; r < 4; r++)
        P[(fm * 16 + lg * 4 + r) * HD_ + fn * 16 + l15] = acc[fm][fn][r];
}

// ---------------------------------------------------------------- K4: reduce partials, scale by 1/(|q||k|)*temp, softmax,
//      compose M[b] = proj_w @ blockdiag(attn)  (bf16 out)
__global__ __launch_bounds__(256)
void k_smax(const float* __restrict__ part, const float* __restrict__ sumsq,
            const float* __restrict__ temp, const float* __restrict__ projw,
            unsigned short* __restrict__ M)
{
  const int h = blockIdx.x, b = blockIdx.y;
  const int tid = threadIdx.x;
  __shared__ float lgt[HD_][HD_];
  __shared__ float at[HD_][HD_];
  __shared__ float pw[C_][HD_];
  const float tmp = temp[h];
  const float* P = part + ((size_t)(b * NH_ + h)) * 256 * (HD_ * HD_);

  for (int e = tid; e < HD_ * HD_; e += 256) {
    float s = 0.f;
    for (int p = 0; p < 256; p++) s += P[(size_t)p * (HD_ * HD_) + e];
    int c = e / HD_, d = e % HD_;
    float nq = fmaxf(sqrtf(sumsq[b * 2 * C_ + h * HD_ + c]), 1e-12f);
    float nk = fmaxf(sqrtf(sumsq[b * 2 * C_ + C_ + h * HD_ + d]), 1e-12f);
    lgt[c][d] = s / (nq * nk) * tmp;
  }
  for (int e = tid; e < C_ * HD_; e += 256) {
    int o = e / HD_, c = e % HD_;
    pw[o][c] = projw[o * C_ + h * HD_ + c];
  }
  __syncthreads();
  if (tid < HD_) {
    float mx = -1e30f;
    for (int d = 0; d < HD_; d++) mx = fmaxf(mx, lgt[tid][d]);
    float s = 0.f;
    for (int d = 0; d < HD_; d++) { float e_ = expf(lgt[tid][d] - mx); at[tid][d] = e_; s += e_; }
    float inv = 1.f / s;
    for (int d = 0; d < HD_; d++) at[tid][d] *= inv;
  }
  __syncthreads();
  unsigned short* Mo = M + (size_t)b * C_ * C_;
  for (int e = tid; e < C_ * HD_; e += 256) {
    int o = e / HD_, d = e % HD_;
    float s = 0.f;
    for (int c = 0; c < HD_; c++) s += pw[o][c] * at[c][d];
    Mo[o * C_ + h * HD_ + d] = f2bf(s);
  }
}

// ----------------------------------------------------------------
extern "C" void kernel_launch(void* const* d_in, const int* in_sizes, int n_in,
                              void* d_out, int out_size, void* d_ws, size_t ws_size,
                              hipStream_t stream)
{
  const float* x     = (const float*)d_in[0];
  const float* qkvw  = (const float*)d_in[1];
  const float* dww   = (const float*)d_in[2];
  const float* projw = (const float*)d_in[3];
  const float* temp  = (const float*)d_in[4];
  float* out         = (float*)d_out;

  char* ws = (char*)d_ws;
  size_t off = 0;
  auto alloc = [&](size_t bytes) { void* p = ws + off; off += (bytes + 255) & ~(size_t)255; return p; };
  unsigned short* qkvw_bf = (unsigned short*)alloc((size_t)CO_ * C_ * 2);
  unsigned short* M_bf    = (unsigned short*)alloc((size_t)B_ * C_ * C_ * 2);
  float* sumsq            = (float*)alloc((size_t)B_ * 2 * C_ * 4);
  float* part             = (float*)alloc((size_t)B_ * NH_ * 256 * HD_ * HD_ * 4);
  unsigned short* qkv_bf  = (unsigned short*)alloc((size_t)B_ * CO_ * NSP_ * 2);
  unsigned short* qkvd_bf = (unsigned short*)alloc((size_t)B_ * CO_ * NSP_ * 2);

  hipMemsetAsync(sumsq, 0, (size_t)B_ * 2 * C_ * 4, stream);
  k_cvt<<<dim3((CO_ * C_ + 255) / 256), dim3(256), 0, stream>>>(qkvw, qkvw_bf, CO_ * C_);
  // K1: qkv = qkv_w @ x    (M=576 via 3 m-blocks, bf16 out)
  k_gemm<3, false, true><<<dim3(3 * 1024, 1, B_), dim3(256), 0, stream>>>(
      qkvw_bf, 0, x, (long)C_ * NSP_, 0, qkv_bf, (long)CO_ * NSP_);
  // K2: depthwise 3x3 + q/k sum-of-squares (vectorized, no LDS)
  k_dw<<<dim3(HGT_ / (8 * DW_RT), CO_, B_), dim3(256), 0, stream>>>(qkv_bf, dww, qkvd_bf, sumsq);
  // K3: q.k^T partials
  k_qk<<<dim3(64, NH_, B_), dim3(256), 0, stream>>>(qkvd_bf, part);
  // K4: softmax + fold proj_w -> M[b] (192x192 bf16)
  k_smax<<<dim3(NH_, B_), dim3(256), 0, stream>>>(part, sumsq, temp, projw, M_bf);
  // K5: out = M[b] @ v   (fp32 out to d_out)
  k_gemm<1, true, false><<<dim3(1024, 1, B_), dim3(256), 0, stream>>>(
      M_bf, (long)C_ * C_, qkvd_bf, (long)CO_ * NSP_, 2 * C_, out, (long)C_ * NSP_);
}

// Round 3
// 391.323 us; speedup vs baseline: 1.3739x; 1.1580x over previous
//
#include <hip/hip_runtime.h>

typedef __attribute__((ext_vector_type(8))) short short8;
typedef __attribute__((ext_vector_type(4))) float f32x4;

#define B_   2
#define C_   192
#define NH_  4
#define HD_  48
#define CO_  576
#define HGT_ 256
#define WID_ 256
#define NSP_ 65536

__device__ __forceinline__ unsigned short f2bf(float f) {
  unsigned int u = __float_as_uint(f);
  u += 0x7FFFu + ((u >> 16) & 1u);   // RNE; inputs are normal floats
  return (unsigned short)(u >> 16);
}
__device__ __forceinline__ float bf2f(unsigned short h) {
  return __uint_as_float(((unsigned int)h) << 16);
}
__device__ __forceinline__ int swz(int n) { return (n & 7) ^ ((n >> 3) & 7); }

// ---------------------------------------------------------------- K0: qkv_w fp32 -> bf16, permuted to MFMA-fragment-linear order
// A_perm[(((m>>4)*6 + (k>>5))*4 + ((k>>3)&3))*16 + (m&15)]*8 + (k&7)] = A[m][k]
__global__ void k_cvtA(const float* __restrict__ src, unsigned short* __restrict__ dst) {
  int i = blockIdx.x * 256 + threadIdx.x;
  if (i >= CO_ * C_) return;
  int m = i / C_, k = i % C_;
  int f = m >> 4, l15 = m & 15, kk = k >> 5, lg = (k >> 3) & 3, j = k & 7;
  dst[((((f * 6 + kk) * 4 + lg) * 16 + l15) << 3) + j] = f2bf(src[i]);
}

// ---------------------------------------------------------------- GEMM: out[b][m][n] = sum_k A[m][k] * X[b][k+chanOff][n]
// Aperm: bf16 fragment-linear (see k_cvtA). X: [b][.][NSP] fp32 or bf16.
// BM=192 (mb), BN=128, K=192 fully staged. 512 threads = 8 waves (4m x 2n);
// wave tile 48x64 => 3x4 frags of 16x16x32 MFMA, operands swapped so D rows = n.
template<int MBLOCKS, bool X_BF16, bool OUT_BF16>
__global__ __launch_bounds__(512)
void k_gemm(const unsigned short* __restrict__ Aperm, long aBatchStride,
            const void* __restrict__ Xin, long xBatchStride, int xChanOff,
            void* __restrict__ Out, long outBatchStride)
{
  __shared__ unsigned short Xs[128 * 192];   // Xs[n][k], XOR-swizzled in 16B units
  const int tid = threadIdx.x;
  const int b = blockIdx.z;
  int mb, nb;
  if (MBLOCKS == 3) {                        // keep the 3 m-blocks sharing an X panel on one XCD
    int lin = blockIdx.x;
    int xcd = lin & 7, rest = lin >> 3;
    mb = rest % 3; nb = (rest / 3) * 8 + xcd;
  } else { mb = 0; nb = blockIdx.x; }

  // ---- stage X panel (192 k-rows x 128 n-cols) -> Xs[n][k] bf16 via 4x4 in-register transpose
  if (!X_BF16) {
    const float* X = (const float*)Xin + (size_t)b * xBatchStride + (size_t)xChanOff * NSP_ + (size_t)nb * 128;
#pragma unroll
    for (int it = 0; it < 3; it++) {
      int s = tid + it * 512;                // 1536 subtiles of 4k x 4n
      int sn = s & 31, sk = s >> 5;
      int n0 = sn * 4, k0 = sk * 4;
      const float* p = X + (size_t)k0 * NSP_ + n0;
      float4 r0 = *(const float4*)(p);
      float4 r1 = *(const float4*)(p + NSP_);
      float4 r2 = *(const float4*)(p + 2 * NSP_);
      float4 r3 = *(const float4*)(p + 3 * NSP_);
      int u16 = k0 >> 3, hh = (k0 >> 2) & 1;
#define WRCOL(J, F) { int n = n0 + (J);                                         \
      unsigned short* q = &Xs[n * 192 + ((u16 ^ swz(n)) << 3) + (hh << 2)];     \
      ushort4 w; w.x = f2bf(r0.F); w.y = f2bf(r1.F); w.z = f2bf(r2.F); w.w = f2bf(r3.F); \
      *(ushort4*)q = w; }
      WRCOL(0, x) WRCOL(1, y) WRCOL(2, z) WRCOL(3, w)
#undef WRCOL
    }
  } else {
    const unsigned short* X = (const unsigned short*)Xin + (size_t)b * xBatchStride + (size_t)xChanOff * NSP_ + (size_t)nb * 128;
#pragma unroll
    for (int it = 0; it < 3; it++) {
      int s = tid + it * 512;
      int sn = s & 31, sk = s >> 5;
      int n0 = sn * 4, k0 = sk * 4;
      const unsigned short* p = X + (size_t)k0 * NSP_ + n0;
      ushort4 r0 = *(const ushort4*)(p);
      ushort4 r1 = *(const ushort4*)(p + NSP_);
      ushort4 r2 = *(const ushort4*)(p + 2 * NSP_);
      ushort4 r3 = *(const ushort4*)(p + 3 * NSP_);
      int u16 = k0 >> 3, hh = (k0 >> 2) & 1;
#define WRCOLU(J, F) { int n = n0 + (J);                                        \
      unsigned short* q = &Xs[n * 192 + ((u16 ^ swz(n)) << 3) + (hh << 2)];     \
      ushort4 w; w.x = r0.F; w.y = r1.F; w.z = r2.F; w.w = r3.F;                \
      *(ushort4*)q = w; }
      WRCOLU(0, x) WRCOLU(1, y) WRCOLU(2, z) WRCOLU(3, w)
#undef WRCOLU
    }
  }
  __syncthreads();

  const int wave = tid >> 6, lane = tid & 63;
  const int wm = wave >> 1, wn = wave & 1;
  const int l15 = lane & 15, lg = lane >> 4;
  const int fragM0 = mb * 12 + wm * 3;       // A frag index base (16-row units)
  const int colbase = wn * 64;
  const unsigned short* Ap = Aperm + (size_t)b * aBatchStride;

  f32x4 acc[3][4];
#pragma unroll
  for (int i = 0; i < 3; i++)
#pragma unroll
    for (int j = 0; j < 4; j++) acc[i][j] = (f32x4){0.f, 0.f, 0.f, 0.f};

#pragma unroll
  for (int kk = 0; kk < 6; kk++) {
    short8 af[3];
#pragma unroll
    for (int fm = 0; fm < 3; fm++)
      af[fm] = *(const short8*)(Ap + (((size_t)((fragM0 + fm) * 6 + kk) * 64 + lane) << 3));
    const int k0 = kk * 32 + lg * 8;
    short8 bfr[4];
#pragma unroll
    for (int fn = 0; fn < 4; fn++) {
      int col = colbase + fn * 16 + l15;
      bfr[fn] = *(const short8*)(&Xs[col * 192 + (((k0 >> 3) ^ swz(col)) << 3)]);
    }
#pragma unroll
    for (int fm = 0; fm < 3; fm++)
#pragma unroll
      for (int fn = 0; fn < 4; fn++)   // swapped operands: D rows = n, cols = m
        acc[fm][fn] = __builtin_amdgcn_mfma_f32_16x16x32_bf16(bfr[fn], af[fm], acc[fm][fn], 0, 0, 0);
  }

  // D layout (swapped): lane l15 = m-row (within frag), lg*4+r = n-col -> 4 consecutive n per lane
  const size_t ncol0 = (size_t)nb * 128 + colbase;
  if (OUT_BF16) {
    unsigned short* O = (unsigned short*)Out + (size_t)b * outBatchStride;
#pragma unroll
    for (int fm = 0; fm < 3; fm++) {
      int m = (fragM0 + fm) * 16 + l15;
#pragma unroll
      for (int fn = 0; fn < 4; fn++) {
        ushort4 w;
        w.x = f2bf(acc[fm][fn][0]); w.y = f2bf(acc[fm][fn][1]);
        w.z = f2bf(acc[fm][fn][2]); w.w = f2bf(acc[fm][fn][3]);
        *(ushort4*)(O + (size_t)m * NSP_ + ncol0 + fn * 16 + lg * 4) = w;
      }
    }
  } else {
    float* O = (float*)Out + (size_t)b * outBatchStride;
#pragma unroll
    for (int fm = 0; fm < 3; fm++) {
      int m = (fragM0 + fm) * 16 + l15;
#pragma unroll
      for (int fn = 0; fn < 4; fn++)
        *(f32x4*)(O + (size_t)m * NSP_ + ncol0 + fn * 16 + lg * 4) = acc[fm][fn];
    }
  }
}

// ---------------------------------------------------------------- K2: depthwise 3x3 (pad 1) + sumsq of q,k channels
// No LDS staging: short8 vector loads, horizontal halo via __shfl within
// 32-lane groups, vertical halo via rolling 3-row register window.
#define DW_RT 16
__global__ __launch_bounds__(256)
void k_dw(const unsigned short* __restrict__ qkv, const float* __restrict__ dww,
          unsigned short* __restrict__ out, float* __restrict__ sumsq)
{
  const int ch = blockIdx.y;
  const int b  = blockIdx.z;
  const int tid = threadIdx.x;
  const int seg = tid & 31;                  // column segment (8 px)
  const int rb  = tid >> 5;                  // row-block 0..7
  const int ybase = blockIdx.x * (8 * DW_RT) + rb * DW_RT;

  const unsigned short* in = qkv + ((size_t)b * CO_ + ch) * NSP_;
  unsigned short* o = out + ((size_t)b * CO_ + ch) * NSP_;
  float w[9];
#pragma unroll
  for (int i = 0; i < 9; i++) w[i] = dww[ch * 9 + i];

  float rw[3][10];
  float ss = 0.f;
#pragma unroll
  for (int i = 0; i < DW_RT + 2; i++) {
    const int yy = ybase - 1 + i;
    float* f = rw[i % 3];
    if ((unsigned)yy < (unsigned)HGT_) {
      short8 v = *(const short8*)(in + (size_t)yy * WID_ + seg * 8);
#pragma unroll
      for (int j = 0; j < 8; j++) f[j + 1] = bf2f((unsigned short)v[j]);
    } else {
#pragma unroll
      for (int j = 0; j < 8; j++) f[j + 1] = 0.f;
    }
    float lf = __shfl_up(f[8], 1, 32);
    float rt = __shfl_down(f[1], 1, 32);
    f[0] = (seg == 0)  ? 0.f : lf;
    f[9] = (seg == 31) ? 0.f : rt;
    if (i >= 2) {
      const float* a  = rw[(i - 2) % 3];
      const float* bb = rw[(i - 1) % 3];
      const float* cc = f;
      short8 ov;
#pragma unroll
      for (int j = 0; j < 8; j++) {
        float acc = a[j]  * w[0] + a[j + 1]  * w[1] + a[j + 2]  * w[2]
                  + bb[j] * w[3] + bb[j + 1] * w[4] + bb[j + 2] * w[5]
                  + cc[j] * w[6] + cc[j + 1] * w[7] + cc[j + 2] * w[8];
        ov[j] = (short)f2bf(acc);
        ss += acc * acc;
      }
      *(short8*)(o + (size_t)(yy - 1) * WID_ + seg * 8) = ov;
    }
  }

  if (ch < 2 * C_) {                          // only q,k channels need norms
#pragma unroll
    for (int off = 32; off > 0; off >>= 1) ss += __shfl_down(ss, off);
    __shared__ float wsum[4];
    if ((tid & 63) == 0) wsum[tid >> 6] = ss;
    __syncthreads();
    if (tid == 0) atomicAdd(&sumsq[b * 2 * C_ + ch], wsum[0] + wsum[1] + wsum[2] + wsum[3]);
  }
}

// ---------------------------------------------------------------- K3: per-(b,h) q.k^T partials over n-chunks (MFMA)
__global__ __launch_bounds__(256)
void k_qk(const unsigned short* __restrict__ qkvd, float* __restrict__ part)
{
  const int chunk = blockIdx.x;               // 64 chunks of 1024 n
  const int h = blockIdx.y, b = blockIdx.z;
  const int wave = threadIdx.x >> 6, lane = threadIdx.x & 63;
  const int l15 = lane & 15, lg = lane >> 4;
  const unsigned short* qb = qkvd + (size_t)b * CO_ * NSP_ + (size_t)(h * HD_) * NSP_;
  const unsigned short* kb = qkvd + (size_t)b * CO_ * NSP_ + (size_t)(C_ + h * HD_) * NSP_;
  const int kbase = chunk * 1024 + wave * 256;

  f32x4 acc[3][3];
#pragma unroll
  for (int i = 0; i < 3; i++)
#pragma unroll
    for (int j = 0; j < 3; j++) acc[i][j] = (f32x4){0.f, 0.f, 0.f, 0.f};

#pragma unroll
  for (int ks = 0; ks < 8; ks++) {
    const int k0 = kbase + ks * 32 + lg * 8;
    short8 af[3], bfr[3];
#pragma unroll
    for (int i = 0; i < 3; i++)
      af[i] = *(const short8*)(qb + (size_t)(i * 16 + l15) * NSP_ + k0);
#pragma unroll
    for (int i = 0; i < 3; i++)
      bfr[i] = *(const short8*)(kb + (size_t)(i * 16 + l15) * NSP_ + k0);
#pragma unroll
    for (int fm = 0; fm < 3; fm++)
#pragma unroll
      for (int fn = 0; fn < 3; fn++)
        acc[fm][fn] = __builtin_amdgcn_mfma_f32_16x16x32_bf16(af[fm], bfr[fn], acc[fm][fn], 0, 0, 0);
  }
  float* P = part + ((((size_t)b * NH_ + h) * 64 + chunk) * 4 + wave) * (HD_ * HD_);
#pragma unroll
  for (int fm = 0; fm < 3; fm++)
#pragma unroll
    for (int fn = 0; fn < 3; fn++)
#pragma unroll
      for (int r = 0; r < 4; r++)
        P[(fm * 16 + lg * 4 + r) * HD_ + fn * 16 + l15] = acc[fm][fn][r];
}

// ---------------------------------------------------------------- K4: reduce partials, scale by 1/(|q||k|)*temp, softmax,
//      compose M[b] = proj_w @ blockdiag(attn), stored fragment-permuted bf16
__global__ __launch_bounds__(256)
void k_smax(const float* __restrict__ part, const float* __restrict__ sumsq,
            const float* __restrict__ temp, const float* __restrict__ projw,
            unsigned short* __restrict__ M)
{
  const int h = blockIdx.x, b = blockIdx.y;
  const int tid = threadIdx.x;
  __shared__ float lgt[HD_][HD_];
  __shared__ float at[HD_][HD_];
  __shared__ float pw[C_][HD_];
  const float tmp = temp[h];
  const float* P = part + ((size_t)(b * NH_ + h)) * 256 * (HD_ * HD_);

  for (int e = tid; e < HD_ * HD_; e += 256) {
    float s = 0.f;
    for (int p = 0; p < 256; p++) s += P[(size_t)p * (HD_ * HD_) + e];
    int c = e / HD_, d = e % HD_;
    float nq = fmaxf(sqrtf(sumsq[b * 2 * C_ + h * HD_ + c]), 1e-12f);
    float nk = fmaxf(sqrtf(sumsq[b * 2 * C_ + C_ + h * HD_ + d]), 1e-12f);
    lgt[c][d] = s / (nq * nk) * tmp;
  }
  for (int e = tid; e < C_ * HD_; e += 256) {
    int o = e / HD_, c = e % HD_;
    pw[o][c] = projw[o * C_ + h * HD_ + c];
  }
  __syncthreads();
  if (tid < HD_) {
    float mx = -1e30f;
    for (int d = 0; d < HD_; d++) mx = fmaxf(mx, lgt[tid][d]);
    float s = 0.f;
    for (int d = 0; d < HD_; d++) { float e_ = expf(lgt[tid][d] - mx); at[tid][d] = e_; s += e_; }
    float inv = 1.f / s;
    for (int d = 0; d < HD_; d++) at[tid][d] *= inv;
  }
  __syncthreads();
  unsigned short* Mo = M + (size_t)b * C_ * C_;
  for (int e = tid; e < C_ * HD_; e += 256) {
    int o = e / HD_, d = e % HD_;
    float s = 0.f;
    for (int c = 0; c < HD_; c++) s += pw[o][c] * at[c][d];
    int col = h * HD_ + d;                    // fragment-permuted index (see k_cvtA)
    int f = o >> 4, l15 = o & 15, kk = col >> 5, lg = (col >> 3) & 3, j = col & 7;
    Mo[((((f * 6 + kk) * 4 + lg) * 16 + l15) << 3) + j] = f2bf(s);
  }
}

// ----------------------------------------------------------------
extern "C" void kernel_launch(void* const* d_in, const int* in_sizes, int n_in,
                              void* d_out, int out_size, void* d_ws, size_t ws_size,
                              hipStream_t stream)
{
  const float* x     = (const float*)d_in[0];
  const float* qkvw  = (const float*)d_in[1];
  const float* dww   = (const float*)d_in[2];
  const float* projw = (const float*)d_in[3];
  const float* temp  = (const float*)d_in[4];
  float* out         = (float*)d_out;

  char* ws = (char*)d_ws;
  size_t off = 0;
  auto alloc = [&](size_t bytes) { void* p = ws + off; off += (bytes + 255) & ~(size_t)255; return p; };
  unsigned short* qkvw_bf = (unsigned short*)alloc((size_t)CO_ * C_ * 2);
  unsigned short* M_bf    = (unsigned short*)alloc((size_t)B_ * C_ * C_ * 2);
  float* sumsq            = (float*)alloc((size_t)B_ * 2 * C_ * 4);
  float* part             = (float*)alloc((size_t)B_ * NH_ * 256 * HD_ * HD_ * 4);
  unsigned short* qkv_bf  = (unsigned short*)alloc((size_t)B_ * CO_ * NSP_ * 2);
  unsigned short* qkvd_bf = (unsigned short*)alloc((size_t)B_ * CO_ * NSP_ * 2);

  hipMemsetAsync(sumsq, 0, (size_t)B_ * 2 * C_ * 4, stream);
  k_cvtA<<<dim3((CO_ * C_ + 255) / 256), dim3(256), 0, stream>>>(qkvw, qkvw_bf);
  // K1: qkv = qkv_w @ x    (M=576 via 3 m-blocks, bf16 out)
  k_gemm<3, false, true><<<dim3(3 * 512, 1, B_), dim3(512), 0, stream>>>(
      qkvw_bf, 0, x, (long)C_ * NSP_, 0, qkv_bf, (long)CO_ * NSP_);
  // K2: depthwise 3x3 + q/k sum-of-squares (vectorized, no LDS)
  k_dw<<<dim3(HGT_ / (8 * DW_RT), CO_, B_), dim3(256), 0, stream>>>(qkv_bf, dww, qkvd_bf, sumsq);
  // K3: q.k^T partials
  k_qk<<<dim3(64, NH_, B_), dim3(256), 0, stream>>>(qkvd_bf, part);
  // K4: softmax + fold proj_w -> M[b] (192x192 bf16, fragment-permuted)
  k_smax<<<dim3(NH_, B_), dim3(256), 0, stream>>>(part, sumsq, temp, projw, M_bf);
  // K5: out = M[b] @ v   (fp32 out to d_out)
  k_gemm<1, true, false><<<dim3(512, 1, B_), dim3(512), 0, stream>>>(
      M_bf, (long)C_ * C_, qkvd_bf, (long)CO_ * NSP_, 2 * C_, out, (long)C_ * NSP_);
}

// Round 4
// 303.897 us; speedup vs baseline: 1.7691x; 1.2877x over previous
//
#include <hip/hip_runtime.h>

typedef __attribute__((ext_vector_type(8))) short short8;
typedef __attribute__((ext_vector_type(4))) float f32x4;

#define B_   2
#define C_   192
#define NH_  4
#define HD_  48
#define CO_  576
#define HGT_ 256
#define WID_ 256
#define NSP_ 65536

__device__ __forceinline__ unsigned short f2bf(float f) {
  unsigned int u = __float_as_uint(f);
  u += 0x7FFFu + ((u >> 16) & 1u);   // RNE; inputs are normal floats
  return (unsigned short)(u >> 16);
}
__device__ __forceinline__ float bf2f(unsigned short h) {
  return __uint_as_float(((unsigned int)h) << 16);
}
__device__ __forceinline__ int swz(int n) { return (n & 7) ^ ((n >> 3) & 7); }

// ---------------------------------------------------------------- K0: qkv_w fp32 -> bf16, permuted to MFMA-fragment-linear order
// A_perm[(((m>>4)*6 + (k>>5))*4 + ((k>>3)&3))*16 + (m&15)]*8 + (k&7)] = A[m][k]
__global__ void k_cvtA(const float* __restrict__ src, unsigned short* __restrict__ dst) {
  int i = blockIdx.x * 256 + threadIdx.x;
  if (i >= CO_ * C_) return;
  int m = i / C_, k = i % C_;
  int f = m >> 4, l15 = m & 15, kk = k >> 5, lg = (k >> 3) & 3, j = k & 7;
  dst[((((f * 6 + kk) * 4 + lg) * 16 + l15) << 3) + j] = f2bf(src[i]);
}

// ---------------------------------------------------------------- GEMM: out[b][m][n] = sum_k A[m][k] * X[b][k+chanOff][n]
// Aperm: bf16 fragment-linear (see k_cvtA). X: [b][.][NSP] fp32 or bf16.
// BM=192 (mb), BN=128, K=192 fully staged. 512 threads = 8 waves (4m x 2n);
// wave tile 48x64 => 3x4 frags of 16x16x32 MFMA, operands swapped so D rows = n.
template<int MBLOCKS, bool X_BF16, bool OUT_BF16>
__global__ __launch_bounds__(512)
void k_gemm(const unsigned short* __restrict__ Aperm, long aBatchStride,
            const void* __restrict__ Xin, long xBatchStride, int xChanOff,
            void* __restrict__ Out, long outBatchStride)
{
  __shared__ unsigned short Xs[128 * 192];   // Xs[n][k], XOR-swizzled in 16B units
  const int tid = threadIdx.x;
  const int b = blockIdx.z;
  int mb, nb;
  if (MBLOCKS == 3) {                        // keep the 3 m-blocks sharing an X panel on one XCD
    int lin = blockIdx.x;
    int xcd = lin & 7, rest = lin >> 3;
    mb = rest % 3; nb = (rest / 3) * 8 + xcd;
  } else { mb = 0; nb = blockIdx.x; }

  // ---- stage X panel (192 k-rows x 128 n-cols) -> Xs[n][k] bf16 via 4x4 in-register transpose
  if (!X_BF16) {
    const float* X = (const float*)Xin + (size_t)b * xBatchStride + (size_t)xChanOff * NSP_ + (size_t)nb * 128;
#pragma unroll
    for (int it = 0; it < 3; it++) {
      int s = tid + it * 512;                // 1536 subtiles of 4k x 4n
      int sn = s & 31, sk = s >> 5;
      int n0 = sn * 4, k0 = sk * 4;
      const float* p = X + (size_t)k0 * NSP_ + n0;
      float4 r0 = *(const float4*)(p);
      float4 r1 = *(const float4*)(p + NSP_);
      float4 r2 = *(const float4*)(p + 2 * NSP_);
      float4 r3 = *(const float4*)(p + 3 * NSP_);
      int u16 = k0 >> 3, hh = (k0 >> 2) & 1;
#define WRCOL(J, F) { int n = n0 + (J);                                         \
      unsigned short* q = &Xs[n * 192 + ((u16 ^ swz(n)) << 3) + (hh << 2)];     \
      ushort4 w; w.x = f2bf(r0.F); w.y = f2bf(r1.F); w.z = f2bf(r2.F); w.w = f2bf(r3.F); \
      *(ushort4*)q = w; }
      WRCOL(0, x) WRCOL(1, y) WRCOL(2, z) WRCOL(3, w)
#undef WRCOL
    }
  } else {
    const unsigned short* X = (const unsigned short*)Xin + (size_t)b * xBatchStride + (size_t)xChanOff * NSP_ + (size_t)nb * 128;
#pragma unroll
    for (int it = 0; it < 3; it++) {
      int s = tid + it * 512;
      int sn = s & 31, sk = s >> 5;
      int n0 = sn * 4, k0 = sk * 4;
      const unsigned short* p = X + (size_t)k0 * NSP_ + n0;
      ushort4 r0 = *(const ushort4*)(p);
      ushort4 r1 = *(const ushort4*)(p + NSP_);
      ushort4 r2 = *(const ushort4*)(p + 2 * NSP_);
      ushort4 r3 = *(const ushort4*)(p + 3 * NSP_);
      int u16 = k0 >> 3, hh = (k0 >> 2) & 1;
#define WRCOLU(J, F) { int n = n0 + (J);                                        \
      unsigned short* q = &Xs[n * 192 + ((u16 ^ swz(n)) << 3) + (hh << 2)];     \
      ushort4 w; w.x = r0.F; w.y = r1.F; w.z = r2.F; w.w = r3.F;                \
      *(ushort4*)q = w; }
      WRCOLU(0, x) WRCOLU(1, y) WRCOLU(2, z) WRCOLU(3, w)
#undef WRCOLU
    }
  }
  __syncthreads();

  const int wave = tid >> 6, lane = tid & 63;
  const int wm = wave >> 1, wn = wave & 1;
  const int l15 = lane & 15, lg = lane >> 4;
  const int fragM0 = mb * 12 + wm * 3;       // A frag index base (16-row units)
  const int colbase = wn * 64;
  const unsigned short* Ap = Aperm + (size_t)b * aBatchStride;

  f32x4 acc[3][4];
#pragma unroll
  for (int i = 0; i < 3; i++)
#pragma unroll
    for (int j = 0; j < 4; j++) acc[i][j] = (f32x4){0.f, 0.f, 0.f, 0.f};

#pragma unroll
  for (int kk = 0; kk < 6; kk++) {
    short8 af[3];
#pragma unroll
    for (int fm = 0; fm < 3; fm++)
      af[fm] = *(const short8*)(Ap + (((size_t)((fragM0 + fm) * 6 + kk) * 64 + lane) << 3));
    const int k0 = kk * 32 + lg * 8;
    short8 bfr[4];
#pragma unroll
    for (int fn = 0; fn < 4; fn++) {
      int col = colbase + fn * 16 + l15;
      bfr[fn] = *(const short8*)(&Xs[col * 192 + (((k0 >> 3) ^ swz(col)) << 3)]);
    }
#pragma unroll
    for (int fm = 0; fm < 3; fm++)
#pragma unroll
      for (int fn = 0; fn < 4; fn++)   // swapped operands: D rows = n, cols = m
        acc[fm][fn] = __builtin_amdgcn_mfma_f32_16x16x32_bf16(bfr[fn], af[fm], acc[fm][fn], 0, 0, 0);
  }

  // D layout (swapped): lane l15 = m-row (within frag), lg*4+r = n-col -> 4 consecutive n per lane
  const size_t ncol0 = (size_t)nb * 128 + colbase;
  if (OUT_BF16) {
    unsigned short* O = (unsigned short*)Out + (size_t)b * outBatchStride;
#pragma unroll
    for (int fm = 0; fm < 3; fm++) {
      int m = (fragM0 + fm) * 16 + l15;
#pragma unroll
      for (int fn = 0; fn < 4; fn++) {
        ushort4 w;
        w.x = f2bf(acc[fm][fn][0]); w.y = f2bf(acc[fm][fn][1]);
        w.z = f2bf(acc[fm][fn][2]); w.w = f2bf(acc[fm][fn][3]);
        *(ushort4*)(O + (size_t)m * NSP_ + ncol0 + fn * 16 + lg * 4) = w;
      }
    }
  } else {
    float* O = (float*)Out + (size_t)b * outBatchStride;
#pragma unroll
    for (int fm = 0; fm < 3; fm++) {
      int m = (fragM0 + fm) * 16 + l15;
#pragma unroll
      for (int fn = 0; fn < 4; fn++)
        *(f32x4*)(O + (size_t)m * NSP_ + ncol0 + fn * 16 + lg * 4) = acc[fm][fn];
    }
  }
}

// ---------------------------------------------------------------- K2: depthwise 3x3 (pad 1) + sumsq of q,k channels
// No LDS staging: short8 vector loads, horizontal halo via __shfl within
// 32-lane groups, vertical halo via rolling 3-row register window.
#define DW_RT 16
__global__ __launch_bounds__(256)
void k_dw(const unsigned short* __restrict__ qkv, const float* __restrict__ dww,
          unsigned short* __restrict__ out, float* __restrict__ sumsq)
{
  const int ch = blockIdx.y;
  const int b  = blockIdx.z;
  const int tid = threadIdx.x;
  const int seg = tid & 31;                  // column segment (8 px)
  const int rb  = tid >> 5;                  // row-block 0..7
  const int ybase = blockIdx.x * (8 * DW_RT) + rb * DW_RT;

  const unsigned short* in = qkv + ((size_t)b * CO_ + ch) * NSP_;
  unsigned short* o = out + ((size_t)b * CO_ + ch) * NSP_;
  float w[9];
#pragma unroll
  for (int i = 0; i < 9; i++) w[i] = dww[ch * 9 + i];

  float rw[3][10];
  float ss = 0.f;
#pragma unroll
  for (int i = 0; i < DW_RT + 2; i++) {
    const int yy = ybase - 1 + i;
    float* f = rw[i % 3];
    if ((unsigned)yy < (unsigned)HGT_) {
      short8 v = *(const short8*)(in + (size_t)yy * WID_ + seg * 8);
#pragma unroll
      for (int j = 0; j < 8; j++) f[j + 1] = bf2f((unsigned short)v[j]);
    } else {
#pragma unroll
      for (int j = 0; j < 8; j++) f[j + 1] = 0.f;
    }
    float lf = __shfl_up(f[8], 1, 32);
    float rt = __shfl_down(f[1], 1, 32);
    f[0] = (seg == 0)  ? 0.f : lf;
    f[9] = (seg == 31) ? 0.f : rt;
    if (i >= 2) {
      const float* a  = rw[(i - 2) % 3];
      const float* bb = rw[(i - 1) % 3];
      const float* cc = f;
      short8 ov;
#pragma unroll
      for (int j = 0; j < 8; j++) {
        float acc = a[j]  * w[0] + a[j + 1]  * w[1] + a[j + 2]  * w[2]
                  + bb[j] * w[3] + bb[j + 1] * w[4] + bb[j + 2] * w[5]
                  + cc[j] * w[6] + cc[j + 1] * w[7] + cc[j + 2] * w[8];
        ov[j] = (short)f2bf(acc);
        ss += acc * acc;
      }
      *(short8*)(o + (size_t)(yy - 1) * WID_ + seg * 8) = ov;
    }
  }

  if (ch < 2 * C_) {                          // only q,k channels need norms
#pragma unroll
    for (int off = 32; off > 0; off >>= 1) ss += __shfl_down(ss, off);
    __shared__ float wsum[4];
    if ((tid & 63) == 0) wsum[tid >> 6] = ss;
    __syncthreads();
    if (tid == 0) atomicAdd(&sumsq[b * 2 * C_ + ch], wsum[0] + wsum[1] + wsum[2] + wsum[3]);
  }
}

// ---------------------------------------------------------------- K3: per-(b,h) q.k^T partials over n-chunks (MFMA)
// 4 waves x 256 spatial each, then cross-wave LDS reduce -> ONE partial tile per block.
__global__ __launch_bounds__(256)
void k_qk(const unsigned short* __restrict__ qkvd, float* __restrict__ part)
{
  const int chunk = blockIdx.x;               // 64 chunks of 1024 n
  const int h = blockIdx.y, b = blockIdx.z;
  const int tid = threadIdx.x;
  const int wave = tid >> 6, lane = tid & 63;
  const int l15 = lane & 15, lg = lane >> 4;
  const unsigned short* qb = qkvd + (size_t)b * CO_ * NSP_ + (size_t)(h * HD_) * NSP_;
  const unsigned short* kb = qkvd + (size_t)b * CO_ * NSP_ + (size_t)(C_ + h * HD_) * NSP_;
  const int kbase = chunk * 1024 + wave * 256;

  f32x4 acc[3][3];
#pragma unroll
  for (int i = 0; i < 3; i++)
#pragma unroll
    for (int j = 0; j < 3; j++) acc[i][j] = (f32x4){0.f, 0.f, 0.f, 0.f};

#pragma unroll
  for (int ks = 0; ks < 8; ks++) {
    const int k0 = kbase + ks * 32 + lg * 8;
    short8 af[3], bfr[3];
#pragma unroll
    for (int i = 0; i < 3; i++)
      af[i] = *(const short8*)(qb + (size_t)(i * 16 + l15) * NSP_ + k0);
#pragma unroll
    for (int i = 0; i < 3; i++)
      bfr[i] = *(const short8*)(kb + (size_t)(i * 16 + l15) * NSP_ + k0);
#pragma unroll
    for (int fm = 0; fm < 3; fm++)
#pragma unroll
      for (int fn = 0; fn < 3; fn++)
        acc[fm][fn] = __builtin_amdgcn_mfma_f32_16x16x32_bf16(af[fm], bfr[fn], acc[fm][fn], 0, 0, 0);
  }

  __shared__ float red[4][HD_ * HD_];
#pragma unroll
  for (int fm = 0; fm < 3; fm++)
#pragma unroll
    for (int fn = 0; fn < 3; fn++)
#pragma unroll
      for (int r = 0; r < 4; r++)
        red[wave][(fm * 16 + lg * 4 + r) * HD_ + fn * 16 + l15] = acc[fm][fn][r];
  __syncthreads();

  float* P = part + ((size_t)(b * NH_ + h) * 64 + chunk) * (HD_ * HD_);
#pragma unroll
  for (int j = 0; j < 9; j++) {               // 2304 = 9*256
    int e = tid + j * 256;
    P[e] = red[0][e] + red[1][e] + red[2][e] + red[3][e];
  }
}

// ---------------------------------------------------------------- K4: reduce 64 partials (thread-parallel, 9-way ILP),
//      scale by 1/(|q||k|)*temp, softmax, compose M[b] = proj_w @ blockdiag(attn)
//      stored fragment-permuted bf16
__global__ __launch_bounds__(256)
void k_smax(const float* __restrict__ part, const float* __restrict__ sumsq,
            const float* __restrict__ temp, const float* __restrict__ projw,
            unsigned short* __restrict__ M)
{
  const int h = blockIdx.x, b = blockIdx.y;
  const int tid = threadIdx.x;
  __shared__ float lgt[HD_][HD_];
  __shared__ float at[HD_][HD_];
  __shared__ float pw[C_][HD_];
  const float tmp = temp[h];
  const float* P = part + (size_t)(b * NH_ + h) * 64 * (HD_ * HD_);

  float s[9];
#pragma unroll
  for (int j = 0; j < 9; j++) s[j] = 0.f;
  for (int p = 0; p < 64; p++) {
    const float* Pp = P + (size_t)p * (HD_ * HD_);
#pragma unroll
    for (int j = 0; j < 9; j++) s[j] += Pp[tid + j * 256];
  }
#pragma unroll
  for (int j = 0; j < 9; j++) {
    int e = tid + j * 256;
    int c = e / HD_, d = e % HD_;
    float nq = fmaxf(sqrtf(sumsq[b * 2 * C_ + h * HD_ + c]), 1e-12f);
    float nk = fmaxf(sqrtf(sumsq[b * 2 * C_ + C_ + h * HD_ + d]), 1e-12f);
    lgt[c][d] = s[j] / (nq * nk) * tmp;
  }
  for (int e = tid; e < C_ * HD_; e += 256) {
    int o = e / HD_, c = e % HD_;
    pw[o][c] = projw[o * C_ + h * HD_ + c];
  }
  __syncthreads();
  if (tid < HD_) {
    float mx = -1e30f;
    for (int d = 0; d < HD_; d++) mx = fmaxf(mx, lgt[tid][d]);
    float ssum = 0.f;
    for (int d = 0; d < HD_; d++) { float e_ = expf(lgt[tid][d] - mx); at[tid][d] = e_; ssum += e_; }
    float inv = 1.f / ssum;
    for (int d = 0; d < HD_; d++) at[tid][d] *= inv;
  }
  __syncthreads();
  unsigned short* Mo = M + (size_t)b * C_ * C_;
  for (int e = tid; e < C_ * HD_; e += 256) {
    int o = e / HD_, d = e % HD_;
    float sm = 0.f;
    for (int c = 0; c < HD_; c++) sm += pw[o][c] * at[c][d];
    int col = h * HD_ + d;                    // fragment-permuted index (see k_cvtA)
    int f = o >> 4, l15 = o & 15, kk = col >> 5, lg = (col >> 3) & 3, j = col & 7;
    Mo[((((f * 6 + kk) * 4 + lg) * 16 + l15) << 3) + j] = f2bf(sm);
  }
}

// ----------------------------------------------------------------
extern "C" void kernel_launch(void* const* d_in, const int* in_sizes, int n_in,
                              void* d_out, int out_size, void* d_ws, size_t ws_size,
                              hipStream_t stream)
{
  const float* x     = (const float*)d_in[0];
  const float* qkvw  = (const float*)d_in[1];
  const float* dww   = (const float*)d_in[2];
  const float* projw = (const float*)d_in[3];
  const float* temp  = (const float*)d_in[4];
  float* out         = (float*)d_out;

  char* ws = (char*)d_ws;
  size_t off = 0;
  auto alloc = [&](size_t bytes) { void* p = ws + off; off += (bytes + 255) & ~(size_t)255; return p; };
  unsigned short* qkvw_bf = (unsigned short*)alloc((size_t)CO_ * C_ * 2);
  unsigned short* M_bf    = (unsigned short*)alloc((size_t)B_ * C_ * C_ * 2);
  float* sumsq            = (float*)alloc((size_t)B_ * 2 * C_ * 4);
  float* part             = (float*)alloc((size_t)B_ * NH_ * 64 * HD_ * HD_ * 4);
  unsigned short* qkv_bf  = (unsigned short*)alloc((size_t)B_ * CO_ * NSP_ * 2);
  unsigned short* qkvd_bf = (unsigned short*)alloc((size_t)B_ * CO_ * NSP_ * 2);

  hipMemsetAsync(sumsq, 0, (size_t)B_ * 2 * C_ * 4, stream);
  k_cvtA<<<dim3((CO_ * C_ + 255) / 256), dim3(256), 0, stream>>>(qkvw, qkvw_bf);
  // K1: qkv = qkv_w @ x    (M=576 via 3 m-blocks, bf16 out)
  k_gemm<3, false, true><<<dim3(3 * 512, 1, B_), dim3(512), 0, stream>>>(
      qkvw_bf, 0, x, (long)C_ * NSP_, 0, qkv_bf, (long)CO_ * NSP_);
  // K2: depthwise 3x3 + q/k sum-of-squares (vectorized, no LDS)
  k_dw<<<dim3(HGT_ / (8 * DW_RT), CO_, B_), dim3(256), 0, stream>>>(qkv_bf, dww, qkvd_bf, sumsq);
  // K3: q.k^T partials (cross-wave reduced: 64 tiles per (b,h))
  k_qk<<<dim3(64, NH_, B_), dim3(256), 0, stream>>>(qkvd_bf, part);
  // K4: softmax + fold proj_w -> M[b] (192x192 bf16, fragment-permuted)
  k_smax<<<dim3(NH_, B_), dim3(256), 0, stream>>>(part, sumsq, temp, projw, M_bf);
  // K5: out = M[b] @ v   (fp32 out to d_out)
  k_gemm<1, true, false><<<dim3(512, 1, B_), dim3(512), 0, stream>>>(
      M_bf, (long)C_ * C_, qkvd_bf, (long)CO_ * NSP_, 2 * C_, out, (long)C_ * NSP_);
}